// Round 1
// baseline (326.233 us; speedup 1.0000x reference)
//
#include <hip/hip_runtime.h>
#include <hip/hip_bf16.h>
#include <stdint.h>

// RecNN: B=2048, L=256 leaves, F=64, H=128.
// One workgroup (256 thr, 4 waves) per 8 batch elements; DFS over the binary
// tree; all activations in LDS; W_leaf/W_nl held in registers as MFMA B-frags.

#define B_TOT 2048
#define LL    256
#define FF    64
#define HH    128
#define LF    (LL*FF)   // 16384
#define BC    8         // batch elems per block (M=8, padded to 16 for MFMA)
#define NTHR  256

typedef __bf16 v8bf __attribute__((ext_vector_type(8)));
typedef float  v4f  __attribute__((ext_vector_type(4)));

// ---- LDS layout (bytes) ----
#define HST_OFF   0        // 8 stack slots x [16][128] bf16 (swizzled) = 32768
#define DST_OFF   32768    // 8 stack slots x [8][64] f32 (linear)      = 16384
#define HCUR_OFF  49152    // [16][128] bf16 swizzled                   = 4096
#define UBUF_OFF  53248    // [16][128] bf16 swizzled                   = 4096
#define DCUR_OFF  57344    // [8][64] f32 linear                        = 2048
#define STG_OFF   59392    // [16][64] bf16 swizzled (A for K=64 GEMMs) = 2048
#define BL_OFF    61440    // b_leaf f32[128]
#define BN_OFF    61952    // b_nl
#define B1_OFF    62464    // b1
#define B2_OFF    62976    // b2
#define LDS_BYTES 63488

// XOR swizzle: spreads 16 rows' identical 16B column slots over banks (G4).
__device__ __forceinline__ uint32_t swz(uint32_t row, uint32_t byteInRow, uint32_t rowBytes){
    return (row*rowBytes + byteInRow) ^ ((row & 7u) << 4);
}

__device__ __forceinline__ v4f mfma16(v8bf a, v8bf b, v4f c){
    return __builtin_amdgcn_mfma_f32_16x16x32_bf16(a, b, c, 0, 0, 0);
}

// A-fragment: lane l holds rows (l&15), k = k0 + 8*(l>>4) + j  (16B contiguous)
__device__ __forceinline__ v8bf ldA(const char* buf, uint32_t rowBytes, uint32_t k0){
    uint32_t lane = threadIdx.x & 63u;
    uint32_t row  = lane & 15u;
    uint32_t kb   = k0 + ((lane >> 4) << 3);
    return *reinterpret_cast<const v8bf*>(buf + swz(row, kb*2u, rowBytes));
}

// B-fragment (W^T layout): lane l holds col n0+(l&15), k = k0 + 8*(l>>4) + j.
// W is row-major [K][128] fp32 in global; converted to bf16 on load. One-time.
__device__ __forceinline__ v8bf ldW(const float* __restrict__ W, int k0, int n0){
    uint32_t lane = threadIdx.x & 63u;
    int n = n0 + (int)(lane & 15u);
    int k = k0 + (int)((lane >> 4) << 3);
    v8bf r;
    #pragma unroll
    for (int j = 0; j < 8; ++j) r[j] = (__bf16)W[(k + j)*HH + n];
    return r;
}

// Epilogue: D elem r -> [row=(l>>4)*4+r][col=16*ntile+(l&15)]; relu(acc+bias) -> bf16 LDS
__device__ __forceinline__ void epi(char* dst, v4f acc, int ntile, const float* biasLds){
    uint32_t lane = threadIdx.x & 63u;
    int col = (ntile << 4) + (int)(lane & 15u);
    float bv = biasLds[col];
    uint32_t r0 = (lane >> 4) << 2;
    #pragma unroll
    for (int r = 0; r < 4; ++r){
        float v = fmaxf(acc[r] + bv, 0.f);
        *reinterpret_cast<__bf16*>(dst + swz(r0 + r, (uint32_t)col*2u, 256u)) = (__bf16)v;
    }
}

__global__ __launch_bounds__(NTHR, 1)
void recnn_kernel(const float* __restrict__ Xg,
                  const float* __restrict__ Wleaf, const float* __restrict__ bleaf,
                  const float* __restrict__ Wnl,   const float* __restrict__ bnl,
                  const float* __restrict__ W1g,   const float* __restrict__ b1g,
                  const float* __restrict__ W2g,   const float* __restrict__ b2g,
                  const float* __restrict__ W3g,   const float* __restrict__ b3g,
                  float* __restrict__ Yg)
{
    __shared__ __align__(16) char lds[LDS_BYTES];
    const int t    = threadIdx.x;
    const int wave = t >> 6;
    const int base = blockIdx.x * BC;

    char*  HST  = lds + HST_OFF;
    float* DST  = (float*)(lds + DST_OFF);
    char*  HCUR = lds + HCUR_OFF;
    char*  UBUF = lds + UBUF_OFF;
    float* DCUR = (float*)(lds + DCUR_OFF);
    char*  STG  = lds + STG_OFF;
    float* BL   = (float*)(lds + BL_OFF);
    float* BN   = (float*)(lds + BN_OFF);
    float* B1L  = (float*)(lds + B1_OFF);
    float* B2L  = (float*)(lds + B2_OFF);

    if (t < 128){
        BL[t]  = bleaf[t];
        BN[t]  = bnl[t];
        B1L[t] = b1g[t];
        B2L[t] = b2g[t];
    }

    // Persistent weight fragments: wave w owns output cols [32w, 32w+32)
    const int n0  = wave << 5;
    const int nt0 = wave*2, nt1 = wave*2 + 1;
    v8bf wlf[2][2], wnl[12][2];
    #pragma unroll
    for (int kf = 0; kf < 2; ++kf){
        wlf[kf][0] = ldW(Wleaf, kf*32, n0);
        wlf[kf][1] = ldW(Wleaf, kf*32, n0 + 16);
    }
    #pragma unroll
    for (int kf = 0; kf < 12; ++kf){
        wnl[kf][0] = ldW(Wnl, kf*32, n0);
        wnl[kf][1] = ldW(Wnl, kf*32, n0 + 16);
    }

    // x staging: thread t handles (row=t>>5, f=(t&31)*2); prefetch 1 leaf ahead
    const int srow = t >> 5;
    const int sf   = (t & 31) * 2;

    float2 xv = *(const float2*)(Xg + (size_t)(base + srow)*LF + sf);

    int sp = 0;
    for (int leaf = 0; leaf < LL; ++leaf){
        // ---- stage x -> DCUR (f32) + STG (bf16, swizzled); zero pad rows ----
        DCUR[srow*FF + sf]     = xv.x;
        DCUR[srow*FF + sf + 1] = xv.y;
        {
            uint32_t lo = (uint32_t)__builtin_bit_cast(unsigned short, (__bf16)xv.x);
            uint32_t hi = (uint32_t)__builtin_bit_cast(unsigned short, (__bf16)xv.y);
            *reinterpret_cast<uint32_t*>(STG + swz(srow,   (uint32_t)sf*2u, 128u)) = (hi<<16) | lo;
            *reinterpret_cast<uint32_t*>(STG + swz(srow+8, (uint32_t)sf*2u, 128u)) = 0u;
        }
        if (leaf + 1 < LL)
            xv = *(const float2*)(Xg + (size_t)(base + srow)*LF + (size_t)(leaf+1)*FF + sf);
        __syncthreads();

        // ---- leaf: h_cur = relu(stg @ Wleaf + bleaf) ----
        {
            v4f c0 = {0.f,0.f,0.f,0.f}, c1 = {0.f,0.f,0.f,0.f};
            #pragma unroll
            for (int kf = 0; kf < 2; ++kf){
                v8bf a = ldA(STG, 128u, (uint32_t)kf*32u);
                c0 = mfma16(a, wlf[kf][0], c0);
                c1 = mfma16(a, wlf[kf][1], c1);
            }
            epi(HCUR, c0, nt0, BL);
            epi(HCUR, c1, nt1, BL);
        }
        __syncthreads();

        // ---- merges: count = trailing zeros of (leaf+1) ----
        const int nm = __builtin_ctz(leaf + 1);
        for (int m = 0; m < nm; ++m){
            --sp;
            float* dstp = DST + sp*(8*FF);
            char*  hstp = HST + sp*4096;

            // d_new = d_stack + d_cur (f32, exact pairwise order); bf16 copy to STG
            {
                float a = dstp[srow*FF + sf]     + DCUR[srow*FF + sf];
                float b = dstp[srow*FF + sf + 1] + DCUR[srow*FF + sf + 1];
                DCUR[srow*FF + sf]     = a;
                DCUR[srow*FF + sf + 1] = b;
                uint32_t lo = (uint32_t)__builtin_bit_cast(unsigned short, (__bf16)a);
                uint32_t hi = (uint32_t)__builtin_bit_cast(unsigned short, (__bf16)b);
                *reinterpret_cast<uint32_t*>(STG + swz(srow,   (uint32_t)sf*2u, 128u)) = (hi<<16) | lo;
                *reinterpret_cast<uint32_t*>(STG + swz(srow+8, (uint32_t)sf*2u, 128u)) = 0u;
            }
            __syncthreads();

            // u = relu(d_new @ Wleaf + bleaf) -> UBUF
            {
                v4f c0 = {0.f,0.f,0.f,0.f}, c1 = {0.f,0.f,0.f,0.f};
                #pragma unroll
                for (int kf = 0; kf < 2; ++kf){
                    v8bf a = ldA(STG, 128u, (uint32_t)kf*32u);
                    c0 = mfma16(a, wlf[kf][0], c0);
                    c1 = mfma16(a, wlf[kf][1], c1);
                }
                epi(UBUF, c0, nt0, BL);
                epi(UBUF, c1, nt1, BL);
            }
            __syncthreads();

            // h_new = relu([h_left | h_right | u] @ Wnl + bnl) -> HCUR (in place)
            {
                v4f e0={0.f,0.f,0.f,0.f}, o0={0.f,0.f,0.f,0.f};
                v4f e1={0.f,0.f,0.f,0.f}, o1={0.f,0.f,0.f,0.f};
                #pragma unroll
                for (int kf = 0; kf < 12; ++kf){
                    const char* src = (kf < 4) ? hstp : ((kf < 8) ? HCUR : UBUF);
                    v8bf a = ldA(src, 256u, (uint32_t)(kf & 3)*32u);
                    if (kf & 1){ o0 = mfma16(a, wnl[kf][0], o0); o1 = mfma16(a, wnl[kf][1], o1); }
                    else       { e0 = mfma16(a, wnl[kf][0], e0); e1 = mfma16(a, wnl[kf][1], e1); }
                }
                __syncthreads();   // all A-reads of HCUR done before overwrite
                epi(HCUR, e0 + o0, nt0, BN);
                epi(HCUR, e1 + o1, nt1, BN);
            }
            __syncthreads();
        }

        // ---- push cur onto stack ----
        if (leaf + 1 < LL){
            char*  hstp = HST + sp*4096;
            float* dstp = DST + sp*(8*FF);
            ((uint4*)hstp)[t] = ((const uint4*)HCUR)[t];
            if (t < 128) ((float4*)dstp)[t] = ((const float4*)DCUR)[t];
            ++sp;
            __syncthreads();
        }
    }

    // ---- head: z1 = relu(enc@W1+b1); z2 = relu(z1@W2+b2); out = z2@W3+b3 ----
    {
        v8bf w1f[4][2], w2f[4][2];
        #pragma unroll
        for (int kf = 0; kf < 4; ++kf){
            w1f[kf][0] = ldW(W1g, kf*32, n0);
            w1f[kf][1] = ldW(W1g, kf*32, n0 + 16);
            w2f[kf][0] = ldW(W2g, kf*32, n0);
            w2f[kf][1] = ldW(W2g, kf*32, n0 + 16);
        }
        {
            v4f c0 = {0.f,0.f,0.f,0.f}, c1 = {0.f,0.f,0.f,0.f};
            #pragma unroll
            for (int kf = 0; kf < 4; ++kf){
                v8bf a = ldA(HCUR, 256u, (uint32_t)kf*32u);
                c0 = mfma16(a, w1f[kf][0], c0);
                c1 = mfma16(a, w1f[kf][1], c1);
            }
            epi(UBUF, c0, nt0, B1L);
            epi(UBUF, c1, nt1, B1L);
        }
        __syncthreads();
        {
            v4f c0 = {0.f,0.f,0.f,0.f}, c1 = {0.f,0.f,0.f,0.f};
            #pragma unroll
            for (int kf = 0; kf < 4; ++kf){
                v8bf a = ldA(UBUF, 256u, (uint32_t)kf*32u);
                c0 = mfma16(a, w2f[kf][0], c0);
                c1 = mfma16(a, w2f[kf][1], c1);
            }
            __syncthreads();
            epi(HST, c0, nt0, B2L);   // z2 -> stack slot 0 (free now)
            epi(HST, c1, nt1, B2L);
        }
        __syncthreads();

        if (t < 64){
            float w3a = W3g[t], w3b = W3g[t + 64];
            float b3v = b3g[0];
            #pragma unroll
            for (int r = 0; r < 8; ++r){
                float za = (float)*reinterpret_cast<const __bf16*>(HST + swz((uint32_t)r, (uint32_t)t*2u,      256u));
                float zb = (float)*reinterpret_cast<const __bf16*>(HST + swz((uint32_t)r, (uint32_t)(t+64)*2u, 256u));
                float v = za*w3a + zb*w3b;
                #pragma unroll
                for (int off = 32; off >= 1; off >>= 1) v += __shfl_xor(v, off, 64);
                if (t == 0) Yg[base + r] = v + b3v;
            }
        }
    }
}

extern "C" void kernel_launch(void* const* d_in, const int* in_sizes, int n_in,
                              void* d_out, int out_size, void* d_ws, size_t ws_size,
                              hipStream_t stream){
    const float* x     = (const float*)d_in[0];
    const float* Wleaf = (const float*)d_in[1];
    const float* bleaf = (const float*)d_in[2];
    const float* Wnl   = (const float*)d_in[3];
    const float* bnl   = (const float*)d_in[4];
    const float* W1    = (const float*)d_in[5];
    const float* b1    = (const float*)d_in[6];
    const float* W2    = (const float*)d_in[7];
    const float* b2    = (const float*)d_in[8];
    const float* W3    = (const float*)d_in[9];
    const float* b3    = (const float*)d_in[10];
    float* out = (float*)d_out;

    recnn_kernel<<<B_TOT/BC, NTHR, 0, stream>>>(x, Wleaf, bleaf, Wnl, bnl,
                                                W1, b1, W2, b2, W3, b3, out);
}